// Round 13
// baseline (315.604 us; speedup 1.0000x reference)
//
#include <hip/hip_runtime.h>
#include <hip/hip_bf16.h>

#define CH 128

constexpr float BN_EPS = 1e-5f;

typedef short bf16x8 __attribute__((ext_vector_type(8)));
typedef float f32x4  __attribute__((ext_vector_type(4)));
typedef unsigned int u32x2 __attribute__((ext_vector_type(2)));   // nontemporal-compatible uint2

__device__ __forceinline__ unsigned cvtpk_bf16(float lo, float hi) {
    unsigned r;
    asm("v_cvt_pk_bf16_f32 %0, %1, %2" : "=v"(r) : "v"(lo), "v"(hi));
    return r;
}
__device__ __forceinline__ float bf2f_lo(unsigned u) { return __uint_as_float(u << 16); }
__device__ __forceinline__ float bf2f_hi(unsigned u) { return __uint_as_float(u & 0xffff0000u); }

// LDS-only barrier: waits LDS ops, does NOT drain vmcnt -> global prefetch
// loads stay in flight across the barrier (T4 counted-wait principle).
__device__ __forceinline__ void lds_barrier() {
    asm volatile("s_waitcnt lgkmcnt(0)\n\ts_barrier" ::: "memory");
}

union BF8 { bf16x8 v; unsigned u[4]; };

__device__ __forceinline__ bf16x8 pack8(float f0, float f1, float f2, float f3,
                                        float f4, float f5, float f6, float f7) {
    BF8 r;
    r.u[0] = cvtpk_bf16(f0, f1);
    r.u[1] = cvtpk_bf16(f2, f3);
    r.u[2] = cvtpk_bf16(f4, f5);
    r.u[3] = cvtpk_bf16(f6, f7);
    return r.v;
}

// ---------------------------------------------------------------------------
// Kernel U (MFMA): [u|v](n, o) = W1ext(o, :) . x(n, :), bf16 out, node-major.
// ---------------------------------------------------------------------------
__global__ __launch_bounds__(512, 4) void node_linear_kernel(
    const float* __restrict__ x, const float* __restrict__ W1,
    unsigned short* __restrict__ u_bf, unsigned short* __restrict__ v_bf, int N)
{
    __shared__ short xs[64 * 128];   // 16 KB

    const int t = threadIdx.x;
    const int lane = t & 63;
    const int wv = t >> 6;
    const int l15 = lane & 15;
    const int l4 = lane >> 4;
    const int n0 = blockIdx.x * 64;

    bf16x8 wfrag[2][4];
    #pragma unroll
    for (int ot = 0; ot < 2; ++ot) {
        const int o_ = wv * 32 + ot * 16 + l15;
        const float* wrow = (o_ < 128) ? (W1 + (size_t)o_ * 256)
                                       : (W1 + (size_t)(o_ - 128) * 256 + 128);
        #pragma unroll
        for (int kk = 0; kk < 4; ++kk) {
            float4 a = *(const float4*)(wrow + kk * 32 + l4 * 8);
            float4 b = *(const float4*)(wrow + kk * 32 + l4 * 8 + 4);
            wfrag[ot][kk] = pack8(a.x, a.y, a.z, a.w, b.x, b.y, b.z, b.w);
        }
    }

    const int c16 = t & 15;
    const int cb = c16 * 8;
    const int nsl = t >> 4;
    #pragma unroll
    for (int nn = 0; nn < 2; ++nn) {
        const int n_loc = nsl + nn * 32;
        const int n = n0 + n_loc;
        bf16x8 xv = {0, 0, 0, 0, 0, 0, 0, 0};
        if (n < N) {
            float4 a = *(const float4*)(x + (size_t)n * CH + cb);
            float4 b = *(const float4*)(x + (size_t)n * CH + cb + 4);
            xv = pack8(a.x, a.y, a.z, a.w, b.x, b.y, b.z, b.w);
        }
        *(bf16x8*)(xs + n_loc * 128 + (c16 ^ (n_loc & 7)) * 8) = xv;
    }
    __syncthreads();

    unsigned short* ob = (wv < 4) ? u_bf : v_bf;
    const int chb = (wv & 3) * 32;

    #pragma unroll
    for (int g = 0; g < 4; ++g) {
        const int nrow = g * 16 + l15;
        f32x4 D0 = {0.f, 0.f, 0.f, 0.f};
        f32x4 D1 = {0.f, 0.f, 0.f, 0.f};
        #pragma unroll
        for (int kk = 0; kk < 4; ++kk) {
            bf16x8 a = *(const bf16x8*)(xs + nrow * 128 + ((kk * 4 + l4) ^ (l15 & 7)) * 8);
            D0 = __builtin_amdgcn_mfma_f32_16x16x32_bf16(a, wfrag[0][kk], D0, 0, 0, 0);
            D1 = __builtin_amdgcn_mfma_f32_16x16x32_bf16(a, wfrag[1][kk], D1, 0, 0, 0);
        }
        #pragma unroll
        for (int r = 0; r < 4; ++r) {
            const int n = n0 + g * 16 + l4 * 4 + r;
            if (n < N) {
                unsigned pk = cvtpk_bf16(D0[r], D1[r]);
                ob[(size_t)n * CH + chb + l15]      = (unsigned short)pk;
                ob[(size_t)n * CH + chb + 16 + l15] = (unsigned short)(pk >> 16);
            }
        }
    }
}

// ---------------------------------------------------------------------------
// Kernel S1: per-edge stats of (u[src]+v[dst]); b1 folded in at finalize.
// uint2 lanes, 4-edge ILP: 8 gathers in flight/thread.
// ---------------------------------------------------------------------------
__global__ __launch_bounds__(256, 8) void stats1_kernel(
    const unsigned short* __restrict__ u_bf, const unsigned short* __restrict__ v_bf,
    const int* __restrict__ src, const int* __restrict__ dst,
    float* __restrict__ partials, int E)
{
    const int t = threadIdx.x;
    const int c8 = t & 31;          // uint2 index: channels c8*4 .. c8*4+3
    const int eslot = t >> 5;       // 0..7
    const uint2* u2 = (const uint2*)u_bf;
    const uint2* v2 = (const uint2*)v_bf;

    float rs0=0.f, rs1=0.f, rs2=0.f, rs3=0.f;
    float rq0=0.f, rq1=0.f, rq2=0.f, rq3=0.f;

    const int iters = (E + 31) >> 5;
    for (int it = blockIdx.x; it < iters; it += gridDim.x) {
        const int e0 = it * 32 + eslot;
        const int e1 = e0 + 8;
        const int e2 = e0 + 16;
        const int e3 = e0 + 24;
        if (e0 < E) {
            const uint2 a = u2[(size_t)src[e0] * 32 + c8];
            const uint2 b = v2[(size_t)dst[e0] * 32 + c8];
            float h;
            h = bf2f_lo(a.x) + bf2f_lo(b.x); rs0 += h; rq0 += h * h;
            h = bf2f_hi(a.x) + bf2f_hi(b.x); rs1 += h; rq1 += h * h;
            h = bf2f_lo(a.y) + bf2f_lo(b.y); rs2 += h; rq2 += h * h;
            h = bf2f_hi(a.y) + bf2f_hi(b.y); rs3 += h; rq3 += h * h;
        }
        if (e1 < E) {
            const uint2 a = u2[(size_t)src[e1] * 32 + c8];
            const uint2 b = v2[(size_t)dst[e1] * 32 + c8];
            float h;
            h = bf2f_lo(a.x) + bf2f_lo(b.x); rs0 += h; rq0 += h * h;
            h = bf2f_hi(a.x) + bf2f_hi(b.x); rs1 += h; rq1 += h * h;
            h = bf2f_lo(a.y) + bf2f_lo(b.y); rs2 += h; rq2 += h * h;
            h = bf2f_hi(a.y) + bf2f_hi(b.y); rs3 += h; rq3 += h * h;
        }
        if (e2 < E) {
            const uint2 a = u2[(size_t)src[e2] * 32 + c8];
            const uint2 b = v2[(size_t)dst[e2] * 32 + c8];
            float h;
            h = bf2f_lo(a.x) + bf2f_lo(b.x); rs0 += h; rq0 += h * h;
            h = bf2f_hi(a.x) + bf2f_hi(b.x); rs1 += h; rq1 += h * h;
            h = bf2f_lo(a.y) + bf2f_lo(b.y); rs2 += h; rq2 += h * h;
            h = bf2f_hi(a.y) + bf2f_hi(b.y); rs3 += h; rq3 += h * h;
        }
        if (e3 < E) {
            const uint2 a = u2[(size_t)src[e3] * 32 + c8];
            const uint2 b = v2[(size_t)dst[e3] * 32 + c8];
            float h;
            h = bf2f_lo(a.x) + bf2f_lo(b.x); rs0 += h; rq0 += h * h;
            h = bf2f_hi(a.x) + bf2f_hi(b.x); rs1 += h; rq1 += h * h;
            h = bf2f_lo(a.y) + bf2f_lo(b.y); rs2 += h; rq2 += h * h;
            h = bf2f_hi(a.y) + bf2f_hi(b.y); rs3 += h; rq3 += h * h;
        }
    }
    __shared__ float red[256];
    red[t] = 0.f;
    __syncthreads();
    const int c = c8 * 4;
    atomicAdd(&red[c + 0], rs0); atomicAdd(&red[c + 1], rs1);
    atomicAdd(&red[c + 2], rs2); atomicAdd(&red[c + 3], rs3);
    atomicAdd(&red[128 + c + 0], rq0); atomicAdd(&red[128 + c + 1], rq1);
    atomicAdd(&red[128 + c + 2], rq2); atomicAdd(&red[128 + c + 3], rq3);
    __syncthreads();
    partials[(size_t)blockIdx.x * 256 + t] = red[t];
}

// ---------------------------------------------------------------------------
// Finalize: mean/var -> scale/shift. `bias` (nullable) added to mean only.
// ---------------------------------------------------------------------------
__global__ __launch_bounds__(1024) void finalize_kernel(
    const float* __restrict__ partials, int nblocks,
    const float* __restrict__ gamma, const float* __restrict__ beta,
    const float* __restrict__ bias,
    float* __restrict__ scale, float* __restrict__ shift, float invE)
{
    __shared__ float accs[1024], accq[1024];
    const int t = threadIdx.x;
    const int ch = t & 127;
    const int sl = t >> 7;
    float s = 0.f, q = 0.f;
    for (int b = sl; b < nblocks; b += 8) {
        s += partials[(size_t)b * 256 + ch];
        q += partials[(size_t)b * 256 + 128 + ch];
    }
    accs[t] = s; accq[t] = q;
    __syncthreads();
    if (t < 128) {
        float st = 0.f, qt = 0.f;
        #pragma unroll
        for (int k = 0; k < 8; ++k) { st += accs[k * 128 + t]; qt += accq[k * 128 + t]; }
        const float m0 = st * invE;
        const float var = fmaxf(qt * invE - m0 * m0, 0.f);
        const float mean = m0 + (bias ? bias[t] : 0.f);
        const float sc = gamma[t] * rsqrtf(var + BN_EPS);
        scale[t] = sc;
        shift[t] = beta[t] - mean * sc;
    }
}

// ---------------------------------------------------------------------------
// Kernel S2 (MFMA): R6-proven config — TILE 64, double-buffered ybuf +
// 1-deep register-staged prefetch, LDS-only barrier, 64 VGPR / 8 waves-SIMD.
// h2 stores are NON-TEMPORAL (u32x2): h2 has zero reuse here and is read
// once later; keep it out of L2/L3 so it can't evict gathered u/v rows.
// ---------------------------------------------------------------------------
__global__ __launch_bounds__(512, 4) void layer2_kernel(
    const unsigned short* __restrict__ u_bf, const unsigned short* __restrict__ v_bf,
    const int* __restrict__ src, const int* __restrict__ dst,
    const float* __restrict__ b1,
    const float* __restrict__ scale1, const float* __restrict__ shift1,
    const float* __restrict__ W2, const float* __restrict__ b2,
    u32x2* __restrict__ h2raw, float* __restrict__ partials, int E)
{
    __shared__ short ybuf[2][64 * 128];   // 2 x 16 KB
    __shared__ float red[256];

    const int t = threadIdx.x;
    const int lane = t & 63;
    const int wv = t >> 6;
    const int p = wv & 3;       // o base = p*32
    const int h = wv >> 2;      // e-half
    const int l15 = lane & 15;
    const int l4  = lane >> 4;

    // --- stationary W2 A-fragments ---
    bf16x8 wfrag[2][4];
    #pragma unroll
    for (int ot = 0; ot < 2; ++ot) {
        const int o = p * 32 + ot * 16 + l15;
        #pragma unroll
        for (int kk = 0; kk < 4; ++kk) {
            const float* wp = W2 + (size_t)o * CH + kk * 32 + l4 * 8;
            float4 a = *(const float4*)wp;
            float4 bq = *(const float4*)(wp + 4);
            wfrag[ot][kk] = pack8(a.x, a.y, a.z, a.w, bq.x, bq.y, bq.z, bq.w);
        }
    }
    float b2r[2][4];
    #pragma unroll
    for (int ot = 0; ot < 2; ++ot)
        #pragma unroll
        for (int r = 0; r < 4; ++r)
            b2r[ot][r] = b2[p * 32 + ot * 16 + l4 * 4 + r];

    // --- build-phase constants: thread owns channels cb..cb+7 ---
    const int c16 = t & 15;
    const int cb = c16 * 8;
    const int ebase = t >> 4;   // 0..31
    const float4 sca = *(const float4*)(scale1 + cb);
    const float4 scb = *(const float4*)(scale1 + cb + 4);
    const float4 sha = *(const float4*)(shift1 + cb);
    const float4 shb = *(const float4*)(shift1 + cb + 4);
    const float4 b1a = *(const float4*)(b1 + cb);
    const float4 b1b = *(const float4*)(b1 + cb + 4);
    float4 bsa, bsb;   // b1*scale + shift folded
    bsa.x = b1a.x*sca.x + sha.x; bsa.y = b1a.y*sca.y + sha.y;
    bsa.z = b1a.z*sca.z + sha.z; bsa.w = b1a.w*sca.w + sha.w;
    bsb.x = b1b.x*scb.x + shb.x; bsb.y = b1b.y*scb.y + shb.y;
    bsb.z = b1b.z*scb.z + shb.z; bsb.w = b1b.w*scb.w + shb.w;

    float rs[2][4] = {{0.f,0.f,0.f,0.f},{0.f,0.f,0.f,0.f}};
    float rq[2][4] = {{0.f,0.f,0.f,0.f},{0.f,0.f,0.f,0.f}};

    const int ntiles = (E + 63) >> 6;
    const int tstep = gridDim.x;

    // prefetch stage registers (next tile's gather)
    uint4 ua0, va0, ua1, va1;
    int tile = blockIdx.x;
    if (tile < ntiles) {
        const int eA = tile * 64 + ebase;
        const int eB = eA + 32;
        const int cA = eA < E ? eA : E - 1;
        const int cB = eB < E ? eB : E - 1;
        const int sA = src[cA], dA = dst[cA];
        const int sB = src[cB], dB = dst[cB];
        ua0 = *(const uint4*)(u_bf + (size_t)sA * CH + cb);
        va0 = *(const uint4*)(v_bf + (size_t)dA * CH + cb);
        ua1 = *(const uint4*)(u_bf + (size_t)sB * CH + cb);
        va1 = *(const uint4*)(v_bf + (size_t)dB * CH + cb);
    }

    int cur = 0;
    for (; tile < ntiles; tile += tstep) {
        // ---- build y tile from staged registers ----
        {
            const int e = tile * 64 + ebase;
            bf16x8 y8 = {0, 0, 0, 0, 0, 0, 0, 0};
            if (e < E) {
                const float f0 = bf2f_lo(ua0.x) + bf2f_lo(va0.x);
                const float f1 = bf2f_hi(ua0.x) + bf2f_hi(va0.x);
                const float f2 = bf2f_lo(ua0.y) + bf2f_lo(va0.y);
                const float f3 = bf2f_hi(ua0.y) + bf2f_hi(va0.y);
                const float f4 = bf2f_lo(ua0.z) + bf2f_lo(va0.z);
                const float f5 = bf2f_hi(ua0.z) + bf2f_hi(va0.z);
                const float f6 = bf2f_lo(ua0.w) + bf2f_lo(va0.w);
                const float f7 = bf2f_hi(ua0.w) + bf2f_hi(va0.w);
                y8 = pack8(fmaxf(f0 * sca.x + bsa.x, 0.f),
                           fmaxf(f1 * sca.y + bsa.y, 0.f),
                           fmaxf(f2 * sca.z + bsa.z, 0.f),
                           fmaxf(f3 * sca.w + bsa.w, 0.f),
                           fmaxf(f4 * scb.x + bsb.x, 0.f),
                           fmaxf(f5 * scb.y + bsb.y, 0.f),
                           fmaxf(f6 * scb.z + bsb.z, 0.f),
                           fmaxf(f7 * scb.w + bsb.w, 0.f));
            }
            *(bf16x8*)(ybuf[cur] + ebase * 128 + (c16 ^ (ebase & 7)) * 8) = y8;
        }
        {
            const int e_loc = ebase + 32;
            const int e = tile * 64 + e_loc;
            bf16x8 y8 = {0, 0, 0, 0, 0, 0, 0, 0};
            if (e < E) {
                const float f0 = bf2f_lo(ua1.x) + bf2f_lo(va1.x);
                const float f1 = bf2f_hi(ua1.x) + bf2f_hi(va1.x);
                const float f2 = bf2f_lo(ua1.y) + bf2f_lo(va1.y);
                const float f3 = bf2f_hi(ua1.y) + bf2f_hi(va1.y);
                const float f4 = bf2f_lo(ua1.z) + bf2f_lo(va1.z);
                const float f5 = bf2f_hi(ua1.z) + bf2f_hi(va1.z);
                const float f6 = bf2f_lo(ua1.w) + bf2f_lo(va1.w);
                const float f7 = bf2f_hi(ua1.w) + bf2f_hi(va1.w);
                y8 = pack8(fmaxf(f0 * sca.x + bsa.x, 0.f),
                           fmaxf(f1 * sca.y + bsa.y, 0.f),
                           fmaxf(f2 * sca.z + bsa.z, 0.f),
                           fmaxf(f3 * sca.w + bsa.w, 0.f),
                           fmaxf(f4 * scb.x + bsb.x, 0.f),
                           fmaxf(f5 * scb.y + bsb.y, 0.f),
                           fmaxf(f6 * scb.z + bsb.z, 0.f),
                           fmaxf(f7 * scb.w + bsb.w, 0.f));
            }
            *(bf16x8*)(ybuf[cur] + e_loc * 128 + (c16 ^ (ebase & 7)) * 8) = y8;
        }

        // ---- issue next tile's gather (stays in flight across barrier) ----
        const int ntile = tile + tstep;
        if (ntile < ntiles) {
            const int eA = ntile * 64 + ebase;
            const int eB = eA + 32;
            const int cA = eA < E ? eA : E - 1;
            const int cB = eB < E ? eB : E - 1;
            const int sA = src[cA], dA = dst[cA];
            const int sB = src[cB], dB = dst[cB];
            ua0 = *(const uint4*)(u_bf + (size_t)sA * CH + cb);
            va0 = *(const uint4*)(v_bf + (size_t)dA * CH + cb);
            ua1 = *(const uint4*)(u_bf + (size_t)sB * CH + cb);
            va1 = *(const uint4*)(v_bf + (size_t)dB * CH + cb);
        }

        lds_barrier();   // LDS-only: vmcnt stays outstanding

        // ---- MFMA + epilogue ----
        #pragma unroll
        for (int g2 = 0; g2 < 2; ++g2) {
            const int g = h * 2 + g2;
            const int erow = g * 16 + l15;
            f32x4 D0 = {0.f, 0.f, 0.f, 0.f};
            f32x4 D1 = {0.f, 0.f, 0.f, 0.f};
            #pragma unroll
            for (int kk = 0; kk < 4; ++kk) {
                bf16x8 yf = *(const bf16x8*)(ybuf[cur] + erow * 128 + ((kk * 4 + l4) ^ (l15 & 7)) * 8);
                D0 = __builtin_amdgcn_mfma_f32_16x16x32_bf16(wfrag[0][kk], yf, D0, 0, 0, 0);
                D1 = __builtin_amdgcn_mfma_f32_16x16x32_bf16(wfrag[1][kk], yf, D1, 0, 0, 0);
            }
            const int gblk = tile * 4 + g;
            const bool ev = ((size_t)gblk * 16 + l15) < (size_t)E;
            {   // ot = 0
                const float a0 = D0[0] + b2r[0][0], a1 = D0[1] + b2r[0][1];
                const float a2 = D0[2] + b2r[0][2], a3 = D0[3] + b2r[0][3];
                rs[0][0] += ev ? a0 : 0.f; rq[0][0] += ev ? a0 * a0 : 0.f;
                rs[0][1] += ev ? a1 : 0.f; rq[0][1] += ev ? a1 * a1 : 0.f;
                rs[0][2] += ev ? a2 : 0.f; rq[0][2] += ev ? a2 * a2 : 0.f;
                rs[0][3] += ev ? a3 : 0.f; rq[0][3] += ev ? a3 * a3 : 0.f;
                u32x2 pk = {cvtpk_bf16(a0, a1), cvtpk_bf16(a2, a3)};
                __builtin_nontemporal_store(pk,
                    &h2raw[((size_t)gblk * 8 + p * 2 + 0) * 64 + lane]);
            }
            {   // ot = 1
                const float c0 = D1[0] + b2r[1][0], c1 = D1[1] + b2r[1][1];
                const float c2 = D1[2] + b2r[1][2], c3 = D1[3] + b2r[1][3];
                rs[1][0] += ev ? c0 : 0.f; rq[1][0] += ev ? c0 * c0 : 0.f;
                rs[1][1] += ev ? c1 : 0.f; rq[1][1] += ev ? c1 * c1 : 0.f;
                rs[1][2] += ev ? c2 : 0.f; rq[1][2] += ev ? c2 * c2 : 0.f;
                rs[1][3] += ev ? c3 : 0.f; rq[1][3] += ev ? c3 * c3 : 0.f;
                u32x2 pk = {cvtpk_bf16(c0, c1), cvtpk_bf16(c2, c3)};
                __builtin_nontemporal_store(pk,
                    &h2raw[((size_t)gblk * 8 + p * 2 + 1) * 64 + lane]);
            }
        }
        cur ^= 1;
    }

    // ---- stats reduction ----
    __syncthreads();
    if (t < 256) red[t] = 0.f;
    __syncthreads();
    #pragma unroll
    for (int ot = 0; ot < 2; ++ot) {
        #pragma unroll
        for (int r = 0; r < 4; ++r) {
            float a = rs[ot][r], b = rq[ot][r];
            #pragma unroll
            for (int m = 1; m <= 8; m <<= 1) {
                a += __shfl_xor(a, m, 64);
                b += __shfl_xor(b, m, 64);
            }
            if (l15 == 0) {
                const int ch = p * 32 + ot * 16 + l4 * 4 + r;
                atomicAdd(&red[ch], a);
                atomicAdd(&red[128 + ch], b);
            }
        }
    }
    __syncthreads();
    if (t < 256) partials[(size_t)blockIdx.x * 256 + t] = red[t];
}

// ---------------------------------------------------------------------------
// Kernel S3: out[e] = b3 + sum_o W3[o]*relu(bn2(h2[e,o])); 2-group ILP.
// h2 reads are non-temporal (streamed once, no retention value).
// ---------------------------------------------------------------------------
__global__ __launch_bounds__(256) void output_kernel(
    const u32x2* __restrict__ h2raw,
    const float* __restrict__ scale2, const float* __restrict__ shift2,
    const float* __restrict__ W3, const float* __restrict__ b3,
    float* __restrict__ out, int E)
{
    __shared__ float sc_s[128], sh_s[128], w3_s[128];
    const int t = threadIdx.x;
    if (t < 128) { sc_s[t] = scale2[t]; sh_s[t] = shift2[t]; w3_s[t] = W3[t]; }
    __syncthreads();
    const int wv = t >> 6;
    const int lane = t & 63;
    const int l15 = lane & 15;
    const int l4 = lane >> 4;
    const float bias = b3[0];
    const int ngrp = (E + 15) >> 4;
    const int gstep = gridDim.x * 4;
    for (int g0 = blockIdx.x * 4 + wv; g0 < ngrp; g0 += 2 * gstep) {
        const int g1 = g0 + gstep;
        float acc0 = 0.f, acc1 = 0.f;
        #pragma unroll
        for (int w = 0; w < 8; ++w) {
            const u32x2 raw = __builtin_nontemporal_load(
                &h2raw[((size_t)g0 * 8 + w) * 64 + lane]);
            const int o = w * 16 + l4 * 4;
            const float4 sc = *(const float4*)(sc_s + o);
            const float4 sh = *(const float4*)(sh_s + o);
            const float4 w3 = *(const float4*)(w3_s + o);
            acc0 += fmaxf(bf2f_lo(raw[0]) * sc.x + sh.x, 0.f) * w3.x;
            acc0 += fmaxf(bf2f_hi(raw[0]) * sc.y + sh.y, 0.f) * w3.y;
            acc0 += fmaxf(bf2f_lo(raw[1]) * sc.z + sh.z, 0.f) * w3.z;
            acc0 += fmaxf(bf2f_hi(raw[1]) * sc.w + sh.w, 0.f) * w3.w;
        }
        if (g1 < ngrp) {
            #pragma unroll
            for (int w = 0; w < 8; ++w) {
                const u32x2 raw = __builtin_nontemporal_load(
                    &h2raw[((size_t)g1 * 8 + w) * 64 + lane]);
                const int o = w * 16 + l4 * 4;
                const float4 sc = *(const float4*)(sc_s + o);
                const float4 sh = *(const float4*)(sh_s + o);
                const float4 w3 = *(const float4*)(w3_s + o);
                acc1 += fmaxf(bf2f_lo(raw[0]) * sc.x + sh.x, 0.f) * w3.x;
                acc1 += fmaxf(bf2f_hi(raw[0]) * sc.y + sh.y, 0.f) * w3.y;
                acc1 += fmaxf(bf2f_lo(raw[1]) * sc.z + sh.z, 0.f) * w3.z;
                acc1 += fmaxf(bf2f_hi(raw[1]) * sc.w + sh.w, 0.f) * w3.w;
            }
        }
        acc0 += __shfl_xor(acc0, 16, 64);
        acc0 += __shfl_xor(acc0, 32, 64);
        acc1 += __shfl_xor(acc1, 16, 64);
        acc1 += __shfl_xor(acc1, 32, 64);
        if (l4 == 0) {
            const int e0 = g0 * 16 + l15;
            if (e0 < E) out[e0] = acc0 + bias;
            if (g1 < ngrp) {
                const int e1 = g1 * 16 + l15;
                if (e1 < E) out[e1] = acc1 + bias;
            }
        }
    }
}

// ---------------------------------------------------------------------------
extern "C" void kernel_launch(void* const* d_in, const int* in_sizes, int n_in,
                              void* d_out, int out_size, void* d_ws, size_t ws_size,
                              hipStream_t stream)
{
    const float* x   = (const float*)d_in[0];
    const int*   ei  = (const int*)d_in[1];
    const float* W1  = (const float*)d_in[2];
    const float* b1  = (const float*)d_in[3];
    const float* g1  = (const float*)d_in[4];
    const float* be1 = (const float*)d_in[5];
    const float* W2  = (const float*)d_in[6];
    const float* b2  = (const float*)d_in[7];
    const float* g2  = (const float*)d_in[8];
    const float* be2 = (const float*)d_in[9];
    const float* W3  = (const float*)d_in[10];
    const float* b3  = (const float*)d_in[11];

    const int N = in_sizes[0] / CH;
    const int E = out_size;
    const int* src = ei;
    const int* dst = ei + E;

    const int S1_BLOCKS = 2048;
    const int S2_BLOCKS = 1024;
    const size_t ngblk = (size_t)((E + 63) >> 6) * 4;   // 16-edge groups, tile-padded

    // workspace layout (16B-aligned)
    unsigned short* u_bf = (unsigned short*)d_ws;              // N*128 bf16
    unsigned short* v_bf = u_bf + (size_t)N * CH;              // N*128 bf16
    u32x2* h2raw = (u32x2*)(v_bf + (size_t)N * CH);            // ngblk*8*64 u32x2
    float* part1 = (float*)(h2raw + ngblk * 8 * 64);           // S1_BLOCKS*256
    float* part2 = part1 + (size_t)S1_BLOCKS * 256;            // S2_BLOCKS*256
    float* scale1 = part2 + (size_t)S2_BLOCKS * 256;
    float* shift1 = scale1 + CH;
    float* scale2 = shift1 + CH;
    float* shift2 = scale2 + CH;
    float* out = (float*)d_out;

    node_linear_kernel<<<(N + 63) / 64, 512, 0, stream>>>(x, W1, u_bf, v_bf, N);
    stats1_kernel<<<S1_BLOCKS, 256, 0, stream>>>(u_bf, v_bf, src, dst, part1, E);
    finalize_kernel<<<1, 1024, 0, stream>>>(part1, S1_BLOCKS, g1, be1, b1,
                                            scale1, shift1, 1.0f / (float)E);
    layer2_kernel<<<S2_BLOCKS, 512, 0, stream>>>(u_bf, v_bf, src, dst, b1, scale1, shift1,
                                                 W2, b2, h2raw, part2, E);
    finalize_kernel<<<1, 1024, 0, stream>>>(part2, S2_BLOCKS, g2, be2, nullptr,
                                            scale2, shift2, 1.0f / (float)E);
    output_kernel<<<2048, 256, 0, stream>>>(h2raw, scale2, shift2, W3, b3, out, E);
}

// Round 14
// 259.734 us; speedup vs baseline: 1.2151x; 1.2151x over previous
//
#include <hip/hip_runtime.h>
#include <hip/hip_bf16.h>

#define CH 128

constexpr float BN_EPS = 1e-5f;

typedef short bf16x8 __attribute__((ext_vector_type(8)));
typedef float f32x4  __attribute__((ext_vector_type(4)));

__device__ __forceinline__ unsigned cvtpk_bf16(float lo, float hi) {
    unsigned r;
    asm("v_cvt_pk_bf16_f32 %0, %1, %2" : "=v"(r) : "v"(lo), "v"(hi));
    return r;
}
__device__ __forceinline__ float bf2f_lo(unsigned u) { return __uint_as_float(u << 16); }
__device__ __forceinline__ float bf2f_hi(unsigned u) { return __uint_as_float(u & 0xffff0000u); }

// LDS-only barrier: waits LDS ops, does NOT drain vmcnt -> global prefetch
// loads stay in flight across the barrier (T4 counted-wait principle).
__device__ __forceinline__ void lds_barrier() {
    asm volatile("s_waitcnt lgkmcnt(0)\n\ts_barrier" ::: "memory");
}

union BF8 { bf16x8 v; unsigned u[4]; };

__device__ __forceinline__ bf16x8 pack8(float f0, float f1, float f2, float f3,
                                        float f4, float f5, float f6, float f7) {
    BF8 r;
    r.u[0] = cvtpk_bf16(f0, f1);
    r.u[1] = cvtpk_bf16(f2, f3);
    r.u[2] = cvtpk_bf16(f4, f5);
    r.u[3] = cvtpk_bf16(f6, f7);
    return r.v;
}

// ---------------------------------------------------------------------------
// Kernel U (MFMA): [u|v](n, o) = W1ext(o, :) . x(n, :), bf16 out, node-major.
// ---------------------------------------------------------------------------
__global__ __launch_bounds__(512, 4) void node_linear_kernel(
    const float* __restrict__ x, const float* __restrict__ W1,
    unsigned short* __restrict__ u_bf, unsigned short* __restrict__ v_bf, int N)
{
    __shared__ short xs[64 * 128];   // 16 KB

    const int t = threadIdx.x;
    const int lane = t & 63;
    const int wv = t >> 6;
    const int l15 = lane & 15;
    const int l4 = lane >> 4;
    const int n0 = blockIdx.x * 64;

    bf16x8 wfrag[2][4];
    #pragma unroll
    for (int ot = 0; ot < 2; ++ot) {
        const int o_ = wv * 32 + ot * 16 + l15;
        const float* wrow = (o_ < 128) ? (W1 + (size_t)o_ * 256)
                                       : (W1 + (size_t)(o_ - 128) * 256 + 128);
        #pragma unroll
        for (int kk = 0; kk < 4; ++kk) {
            float4 a = *(const float4*)(wrow + kk * 32 + l4 * 8);
            float4 b = *(const float4*)(wrow + kk * 32 + l4 * 8 + 4);
            wfrag[ot][kk] = pack8(a.x, a.y, a.z, a.w, b.x, b.y, b.z, b.w);
        }
    }

    const int c16 = t & 15;
    const int cb = c16 * 8;
    const int nsl = t >> 4;
    #pragma unroll
    for (int nn = 0; nn < 2; ++nn) {
        const int n_loc = nsl + nn * 32;
        const int n = n0 + n_loc;
        bf16x8 xv = {0, 0, 0, 0, 0, 0, 0, 0};
        if (n < N) {
            float4 a = *(const float4*)(x + (size_t)n * CH + cb);
            float4 b = *(const float4*)(x + (size_t)n * CH + cb + 4);
            xv = pack8(a.x, a.y, a.z, a.w, b.x, b.y, b.z, b.w);
        }
        *(bf16x8*)(xs + n_loc * 128 + (c16 ^ (n_loc & 7)) * 8) = xv;
    }
    __syncthreads();

    unsigned short* ob = (wv < 4) ? u_bf : v_bf;
    const int chb = (wv & 3) * 32;

    #pragma unroll
    for (int g = 0; g < 4; ++g) {
        const int nrow = g * 16 + l15;
        f32x4 D0 = {0.f, 0.f, 0.f, 0.f};
        f32x4 D1 = {0.f, 0.f, 0.f, 0.f};
        #pragma unroll
        for (int kk = 0; kk < 4; ++kk) {
            bf16x8 a = *(const bf16x8*)(xs + nrow * 128 + ((kk * 4 + l4) ^ (l15 & 7)) * 8);
            D0 = __builtin_amdgcn_mfma_f32_16x16x32_bf16(a, wfrag[0][kk], D0, 0, 0, 0);
            D1 = __builtin_amdgcn_mfma_f32_16x16x32_bf16(a, wfrag[1][kk], D1, 0, 0, 0);
        }
        #pragma unroll
        for (int r = 0; r < 4; ++r) {
            const int n = n0 + g * 16 + l4 * 4 + r;
            if (n < N) {
                unsigned pk = cvtpk_bf16(D0[r], D1[r]);
                ob[(size_t)n * CH + chb + l15]      = (unsigned short)pk;
                ob[(size_t)n * CH + chb + 16 + l15] = (unsigned short)(pk >> 16);
            }
        }
    }
}

// ---------------------------------------------------------------------------
// Kernel S1: per-edge stats of (u[src]+v[dst]); b1 folded in at finalize.
// layer2-mirrored gather: 512 thr, 16 lanes x uint4 per row, 64-edge tiles,
// 1-deep register-staged prefetch issued before the accumulate phase.
// ---------------------------------------------------------------------------
__global__ __launch_bounds__(512, 4) void stats1_kernel(
    const unsigned short* __restrict__ u_bf, const unsigned short* __restrict__ v_bf,
    const int* __restrict__ src, const int* __restrict__ dst,
    float* __restrict__ partials, int E)
{
    const int t = threadIdx.x;
    const int lane = t & 63;
    const int c16 = t & 15;
    const int cb = c16 * 8;
    const int ebase = t >> 4;   // 0..31

    float rs[8] = {0.f,0.f,0.f,0.f,0.f,0.f,0.f,0.f};
    float rq[8] = {0.f,0.f,0.f,0.f,0.f,0.f,0.f,0.f};

    const int ntiles = (E + 63) >> 6;
    const int tstep = gridDim.x;

    // 1-deep staged prefetch (layer2 pattern)
    uint4 ua0, va0, ua1, va1;
    int tile = blockIdx.x;
    if (tile < ntiles) {
        const int eA = tile * 64 + ebase;
        const int eB = eA + 32;
        const int cA = eA < E ? eA : E - 1;
        const int cB = eB < E ? eB : E - 1;
        ua0 = *(const uint4*)(u_bf + (size_t)src[cA] * CH + cb);
        va0 = *(const uint4*)(v_bf + (size_t)dst[cA] * CH + cb);
        ua1 = *(const uint4*)(u_bf + (size_t)src[cB] * CH + cb);
        va1 = *(const uint4*)(v_bf + (size_t)dst[cB] * CH + cb);
    }

    for (; tile < ntiles; tile += tstep) {
        const uint4 cua0 = ua0, cva0 = va0, cua1 = ua1, cva1 = va1;
        const int e0 = tile * 64 + ebase;
        const int e1 = e0 + 32;

        // issue next tile's gather before consuming current (loads in flight
        // across the ~80-VALU accumulate window + TLP)
        const int ntile = tile + tstep;
        if (ntile < ntiles) {
            const int eA = ntile * 64 + ebase;
            const int eB = eA + 32;
            const int cA = eA < E ? eA : E - 1;
            const int cB = eB < E ? eB : E - 1;
            ua0 = *(const uint4*)(u_bf + (size_t)src[cA] * CH + cb);
            va0 = *(const uint4*)(v_bf + (size_t)dst[cA] * CH + cb);
            ua1 = *(const uint4*)(u_bf + (size_t)src[cB] * CH + cb);
            va1 = *(const uint4*)(v_bf + (size_t)dst[cB] * CH + cb);
        }

        if (e0 < E) {
            float h;
            h = bf2f_lo(cua0.x) + bf2f_lo(cva0.x); rs[0] += h; rq[0] += h * h;
            h = bf2f_hi(cua0.x) + bf2f_hi(cva0.x); rs[1] += h; rq[1] += h * h;
            h = bf2f_lo(cua0.y) + bf2f_lo(cva0.y); rs[2] += h; rq[2] += h * h;
            h = bf2f_hi(cua0.y) + bf2f_hi(cva0.y); rs[3] += h; rq[3] += h * h;
            h = bf2f_lo(cua0.z) + bf2f_lo(cva0.z); rs[4] += h; rq[4] += h * h;
            h = bf2f_hi(cua0.z) + bf2f_hi(cva0.z); rs[5] += h; rq[5] += h * h;
            h = bf2f_lo(cua0.w) + bf2f_lo(cva0.w); rs[6] += h; rq[6] += h * h;
            h = bf2f_hi(cua0.w) + bf2f_hi(cva0.w); rs[7] += h; rq[7] += h * h;
        }
        if (e1 < E) {
            float h;
            h = bf2f_lo(cua1.x) + bf2f_lo(cva1.x); rs[0] += h; rq[0] += h * h;
            h = bf2f_hi(cua1.x) + bf2f_hi(cva1.x); rs[1] += h; rq[1] += h * h;
            h = bf2f_lo(cua1.y) + bf2f_lo(cva1.y); rs[2] += h; rq[2] += h * h;
            h = bf2f_hi(cua1.y) + bf2f_hi(cva1.y); rs[3] += h; rq[3] += h * h;
            h = bf2f_lo(cua1.z) + bf2f_lo(cva1.z); rs[4] += h; rq[4] += h * h;
            h = bf2f_hi(cua1.z) + bf2f_hi(cva1.z); rs[5] += h; rq[5] += h * h;
            h = bf2f_lo(cua1.w) + bf2f_lo(cva1.w); rs[6] += h; rq[6] += h * h;
            h = bf2f_hi(cua1.w) + bf2f_hi(cva1.w); rs[7] += h; rq[7] += h * h;
        }
    }

    // wave pre-reduction: lanes l, l+16, l+32, l+48 share c16
    __shared__ float red[256];
    if (t < 256) red[t] = 0.f;
    __syncthreads();
    #pragma unroll
    for (int k = 0; k < 8; ++k) {
        float a = rs[k], b = rq[k];
        a += __shfl_xor(a, 16, 64); a += __shfl_xor(a, 32, 64);
        b += __shfl_xor(b, 16, 64); b += __shfl_xor(b, 32, 64);
        if ((lane & 48) == 0) {
            atomicAdd(&red[cb + k], a);
            atomicAdd(&red[128 + cb + k], b);
        }
    }
    __syncthreads();
    if (t < 256) partials[(size_t)blockIdx.x * 256 + t] = red[t];
}

// ---------------------------------------------------------------------------
// Finalize: mean/var -> scale/shift. `bias` (nullable) added to mean only.
// ---------------------------------------------------------------------------
__global__ __launch_bounds__(1024) void finalize_kernel(
    const float* __restrict__ partials, int nblocks,
    const float* __restrict__ gamma, const float* __restrict__ beta,
    const float* __restrict__ bias,
    float* __restrict__ scale, float* __restrict__ shift, float invE)
{
    __shared__ float accs[1024], accq[1024];
    const int t = threadIdx.x;
    const int ch = t & 127;
    const int sl = t >> 7;
    float s = 0.f, q = 0.f;
    for (int b = sl; b < nblocks; b += 8) {
        s += partials[(size_t)b * 256 + ch];
        q += partials[(size_t)b * 256 + 128 + ch];
    }
    accs[t] = s; accq[t] = q;
    __syncthreads();
    if (t < 128) {
        float st = 0.f, qt = 0.f;
        #pragma unroll
        for (int k = 0; k < 8; ++k) { st += accs[k * 128 + t]; qt += accq[k * 128 + t]; }
        const float m0 = st * invE;
        const float var = fmaxf(qt * invE - m0 * m0, 0.f);
        const float mean = m0 + (bias ? bias[t] : 0.f);
        const float sc = gamma[t] * rsqrtf(var + BN_EPS);
        scale[t] = sc;
        shift[t] = beta[t] - mean * sc;
    }
}

// ---------------------------------------------------------------------------
// Kernel S2 (MFMA): R6/R11-proven config — TILE 64, double-buffered ybuf +
// 1-deep register-staged prefetch, LDS-only barrier, 64 VGPR / 8 waves-SIMD.
// ---------------------------------------------------------------------------
__global__ __launch_bounds__(512, 4) void layer2_kernel(
    const unsigned short* __restrict__ u_bf, const unsigned short* __restrict__ v_bf,
    const int* __restrict__ src, const int* __restrict__ dst,
    const float* __restrict__ b1,
    const float* __restrict__ scale1, const float* __restrict__ shift1,
    const float* __restrict__ W2, const float* __restrict__ b2,
    uint2* __restrict__ h2raw, float* __restrict__ partials, int E)
{
    __shared__ short ybuf[2][64 * 128];   // 2 x 16 KB
    __shared__ float red[256];

    const int t = threadIdx.x;
    const int lane = t & 63;
    const int wv = t >> 6;
    const int p = wv & 3;       // o base = p*32
    const int h = wv >> 2;      // e-half
    const int l15 = lane & 15;
    const int l4  = lane >> 4;

    // --- stationary W2 A-fragments ---
    bf16x8 wfrag[2][4];
    #pragma unroll
    for (int ot = 0; ot < 2; ++ot) {
        const int o = p * 32 + ot * 16 + l15;
        #pragma unroll
        for (int kk = 0; kk < 4; ++kk) {
            const float* wp = W2 + (size_t)o * CH + kk * 32 + l4 * 8;
            float4 a = *(const float4*)wp;
            float4 bq = *(const float4*)(wp + 4);
            wfrag[ot][kk] = pack8(a.x, a.y, a.z, a.w, bq.x, bq.y, bq.z, bq.w);
        }
    }
    float b2r[2][4];
    #pragma unroll
    for (int ot = 0; ot < 2; ++ot)
        #pragma unroll
        for (int r = 0; r < 4; ++r)
            b2r[ot][r] = b2[p * 32 + ot * 16 + l4 * 4 + r];

    // --- build-phase constants: thread owns channels cb..cb+7 ---
    const int c16 = t & 15;
    const int cb = c16 * 8;
    const int ebase = t >> 4;   // 0..31
    const float4 sca = *(const float4*)(scale1 + cb);
    const float4 scb = *(const float4*)(scale1 + cb + 4);
    const float4 sha = *(const float4*)(shift1 + cb);
    const float4 shb = *(const float4*)(shift1 + cb + 4);
    const float4 b1a = *(const float4*)(b1 + cb);
    const float4 b1b = *(const float4*)(b1 + cb + 4);
    float4 bsa, bsb;   // b1*scale + shift folded
    bsa.x = b1a.x*sca.x + sha.x; bsa.y = b1a.y*sca.y + sha.y;
    bsa.z = b1a.z*sca.z + sha.z; bsa.w = b1a.w*sca.w + sha.w;
    bsb.x = b1b.x*scb.x + shb.x; bsb.y = b1b.y*scb.y + shb.y;
    bsb.z = b1b.z*scb.z + shb.z; bsb.w = b1b.w*scb.w + shb.w;

    float rs[2][4] = {{0.f,0.f,0.f,0.f},{0.f,0.f,0.f,0.f}};
    float rq[2][4] = {{0.f,0.f,0.f,0.f},{0.f,0.f,0.f,0.f}};

    const int ntiles = (E + 63) >> 6;
    const int tstep = gridDim.x;

    // prefetch stage registers (next tile's gather)
    uint4 ua0, va0, ua1, va1;
    int tile = blockIdx.x;
    if (tile < ntiles) {
        const int eA = tile * 64 + ebase;
        const int eB = eA + 32;
        const int cA = eA < E ? eA : E - 1;
        const int cB = eB < E ? eB : E - 1;
        const int sA = src[cA], dA = dst[cA];
        const int sB = src[cB], dB = dst[cB];
        ua0 = *(const uint4*)(u_bf + (size_t)sA * CH + cb);
        va0 = *(const uint4*)(v_bf + (size_t)dA * CH + cb);
        ua1 = *(const uint4*)(u_bf + (size_t)sB * CH + cb);
        va1 = *(const uint4*)(v_bf + (size_t)dB * CH + cb);
    }

    int cur = 0;
    for (; tile < ntiles; tile += tstep) {
        // ---- build y tile from staged registers ----
        {
            const int e = tile * 64 + ebase;
            bf16x8 y8 = {0, 0, 0, 0, 0, 0, 0, 0};
            if (e < E) {
                const float f0 = bf2f_lo(ua0.x) + bf2f_lo(va0.x);
                const float f1 = bf2f_hi(ua0.x) + bf2f_hi(va0.x);
                const float f2 = bf2f_lo(ua0.y) + bf2f_lo(va0.y);
                const float f3 = bf2f_hi(ua0.y) + bf2f_hi(va0.y);
                const float f4 = bf2f_lo(ua0.z) + bf2f_lo(va0.z);
                const float f5 = bf2f_hi(ua0.z) + bf2f_hi(va0.z);
                const float f6 = bf2f_lo(ua0.w) + bf2f_lo(va0.w);
                const float f7 = bf2f_hi(ua0.w) + bf2f_hi(va0.w);
                y8 = pack8(fmaxf(f0 * sca.x + bsa.x, 0.f),
                           fmaxf(f1 * sca.y + bsa.y, 0.f),
                           fmaxf(f2 * sca.z + bsa.z, 0.f),
                           fmaxf(f3 * sca.w + bsa.w, 0.f),
                           fmaxf(f4 * scb.x + bsb.x, 0.f),
                           fmaxf(f5 * scb.y + bsb.y, 0.f),
                           fmaxf(f6 * scb.z + bsb.z, 0.f),
                           fmaxf(f7 * scb.w + bsb.w, 0.f));
            }
            *(bf16x8*)(ybuf[cur] + ebase * 128 + (c16 ^ (ebase & 7)) * 8) = y8;
        }
        {
            const int e_loc = ebase + 32;
            const int e = tile * 64 + e_loc;
            bf16x8 y8 = {0, 0, 0, 0, 0, 0, 0, 0};
            if (e < E) {
                const float f0 = bf2f_lo(ua1.x) + bf2f_lo(va1.x);
                const float f1 = bf2f_hi(ua1.x) + bf2f_hi(va1.x);
                const float f2 = bf2f_lo(ua1.y) + bf2f_lo(va1.y);
                const float f3 = bf2f_hi(ua1.y) + bf2f_hi(va1.y);
                const float f4 = bf2f_lo(ua1.z) + bf2f_lo(va1.z);
                const float f5 = bf2f_hi(ua1.z) + bf2f_hi(va1.z);
                const float f6 = bf2f_lo(ua1.w) + bf2f_lo(va1.w);
                const float f7 = bf2f_hi(ua1.w) + bf2f_hi(va1.w);
                y8 = pack8(fmaxf(f0 * sca.x + bsa.x, 0.f),
                           fmaxf(f1 * sca.y + bsa.y, 0.f),
                           fmaxf(f2 * sca.z + bsa.z, 0.f),
                           fmaxf(f3 * sca.w + bsa.w, 0.f),
                           fmaxf(f4 * scb.x + bsb.x, 0.f),
                           fmaxf(f5 * scb.y + bsb.y, 0.f),
                           fmaxf(f6 * scb.z + bsb.z, 0.f),
                           fmaxf(f7 * scb.w + bsb.w, 0.f));
            }
            *(bf16x8*)(ybuf[cur] + e_loc * 128 + (c16 ^ (ebase & 7)) * 8) = y8;
        }

        // ---- issue next tile's gather (stays in flight across barrier) ----
        const int ntile = tile + tstep;
        if (ntile < ntiles) {
            const int eA = ntile * 64 + ebase;
            const int eB = eA + 32;
            const int cA = eA < E ? eA : E - 1;
            const int cB = eB < E ? eB : E - 1;
            const int sA = src[cA], dA = dst[cA];
            const int sB = src[cB], dB = dst[cB];
            ua0 = *(const uint4*)(u_bf + (size_t)sA * CH + cb);
            va0 = *(const uint4*)(v_bf + (size_t)dA * CH + cb);
            ua1 = *(const uint4*)(u_bf + (size_t)sB * CH + cb);
            va1 = *(const uint4*)(v_bf + (size_t)dB * CH + cb);
        }

        lds_barrier();   // LDS-only: vmcnt stays outstanding

        // ---- MFMA + epilogue ----
        #pragma unroll
        for (int g2 = 0; g2 < 2; ++g2) {
            const int g = h * 2 + g2;
            const int erow = g * 16 + l15;
            f32x4 D0 = {0.f, 0.f, 0.f, 0.f};
            f32x4 D1 = {0.f, 0.f, 0.f, 0.f};
            #pragma unroll
            for (int kk = 0; kk < 4; ++kk) {
                bf16x8 yf = *(const bf16x8*)(ybuf[cur] + erow * 128 + ((kk * 4 + l4) ^ (l15 & 7)) * 8);
                D0 = __builtin_amdgcn_mfma_f32_16x16x32_bf16(wfrag[0][kk], yf, D0, 0, 0, 0);
                D1 = __builtin_amdgcn_mfma_f32_16x16x32_bf16(wfrag[1][kk], yf, D1, 0, 0, 0);
            }
            const int gblk = tile * 4 + g;
            const bool ev = ((size_t)gblk * 16 + l15) < (size_t)E;
            {   // ot = 0
                const float a0 = D0[0] + b2r[0][0], a1 = D0[1] + b2r[0][1];
                const float a2 = D0[2] + b2r[0][2], a3 = D0[3] + b2r[0][3];
                rs[0][0] += ev ? a0 : 0.f; rq[0][0] += ev ? a0 * a0 : 0.f;
                rs[0][1] += ev ? a1 : 0.f; rq[0][1] += ev ? a1 * a1 : 0.f;
                rs[0][2] += ev ? a2 : 0.f; rq[0][2] += ev ? a2 * a2 : 0.f;
                rs[0][3] += ev ? a3 : 0.f; rq[0][3] += ev ? a3 * a3 : 0.f;
                h2raw[((size_t)gblk * 8 + p * 2 + 0) * 64 + lane] =
                    make_uint2(cvtpk_bf16(a0, a1), cvtpk_bf16(a2, a3));
            }
            {   // ot = 1
                const float c0 = D1[0] + b2r[1][0], c1 = D1[1] + b2r[1][1];
                const float c2 = D1[2] + b2r[1][2], c3 = D1[3] + b2r[1][3];
                rs[1][0] += ev ? c0 : 0.f; rq[1][0] += ev ? c0 * c0 : 0.f;
                rs[1][1] += ev ? c1 : 0.f; rq[1][1] += ev ? c1 * c1 : 0.f;
                rs[1][2] += ev ? c2 : 0.f; rq[1][2] += ev ? c2 * c2 : 0.f;
                rs[1][3] += ev ? c3 : 0.f; rq[1][3] += ev ? c3 * c3 : 0.f;
                h2raw[((size_t)gblk * 8 + p * 2 + 1) * 64 + lane] =
                    make_uint2(cvtpk_bf16(c0, c1), cvtpk_bf16(c2, c3));
            }
        }
        cur ^= 1;
    }

    // ---- stats reduction ----
    __syncthreads();
    if (t < 256) red[t] = 0.f;
    __syncthreads();
    #pragma unroll
    for (int ot = 0; ot < 2; ++ot) {
        #pragma unroll
        for (int r = 0; r < 4; ++r) {
            float a = rs[ot][r], b = rq[ot][r];
            #pragma unroll
            for (int m = 1; m <= 8; m <<= 1) {
                a += __shfl_xor(a, m, 64);
                b += __shfl_xor(b, m, 64);
            }
            if (l15 == 0) {
                const int ch = p * 32 + ot * 16 + l4 * 4 + r;
                atomicAdd(&red[ch], a);
                atomicAdd(&red[128 + ch], b);
            }
        }
    }
    __syncthreads();
    if (t < 256) partials[(size_t)blockIdx.x * 256 + t] = red[t];
}

// ---------------------------------------------------------------------------
// Kernel S3: out[e] = b3 + sum_o W3[o]*relu(bn2(h2[e,o])); 2-group ILP.
// ---------------------------------------------------------------------------
__global__ __launch_bounds__(256) void output_kernel(
    const uint2* __restrict__ h2raw,
    const float* __restrict__ scale2, const float* __restrict__ shift2,
    const float* __restrict__ W3, const float* __restrict__ b3,
    float* __restrict__ out, int E)
{
    __shared__ float sc_s[128], sh_s[128], w3_s[128];
    const int t = threadIdx.x;
    if (t < 128) { sc_s[t] = scale2[t]; sh_s[t] = shift2[t]; w3_s[t] = W3[t]; }
    __syncthreads();
    const int wv = t >> 6;
    const int lane = t & 63;
    const int l15 = lane & 15;
    const int l4 = lane >> 4;
    const float bias = b3[0];
    const int ngrp = (E + 15) >> 4;
    const int gstep = gridDim.x * 4;
    for (int g0 = blockIdx.x * 4 + wv; g0 < ngrp; g0 += 2 * gstep) {
        const int g1 = g0 + gstep;
        float acc0 = 0.f, acc1 = 0.f;
        #pragma unroll
        for (int w = 0; w < 8; ++w) {
            const uint2 raw = h2raw[((size_t)g0 * 8 + w) * 64 + lane];
            const int o = w * 16 + l4 * 4;
            const float4 sc = *(const float4*)(sc_s + o);
            const float4 sh = *(const float4*)(sh_s + o);
            const float4 w3 = *(const float4*)(w3_s + o);
            acc0 += fmaxf(bf2f_lo(raw.x) * sc.x + sh.x, 0.f) * w3.x;
            acc0 += fmaxf(bf2f_hi(raw.x) * sc.y + sh.y, 0.f) * w3.y;
            acc0 += fmaxf(bf2f_lo(raw.y) * sc.z + sh.z, 0.f) * w3.z;
            acc0 += fmaxf(bf2f_hi(raw.y) * sc.w + sh.w, 0.f) * w3.w;
        }
        if (g1 < ngrp) {
            #pragma unroll
            for (int w = 0; w < 8; ++w) {
                const uint2 raw = h2raw[((size_t)g1 * 8 + w) * 64 + lane];
                const int o = w * 16 + l4 * 4;
                const float4 sc = *(const float4*)(sc_s + o);
                const float4 sh = *(const float4*)(sh_s + o);
                const float4 w3 = *(const float4*)(w3_s + o);
                acc1 += fmaxf(bf2f_lo(raw.x) * sc.x + sh.x, 0.f) * w3.x;
                acc1 += fmaxf(bf2f_hi(raw.x) * sc.y + sh.y, 0.f) * w3.y;
                acc1 += fmaxf(bf2f_lo(raw.y) * sc.z + sh.z, 0.f) * w3.z;
                acc1 += fmaxf(bf2f_hi(raw.y) * sc.w + sh.w, 0.f) * w3.w;
            }
        }
        acc0 += __shfl_xor(acc0, 16, 64);
        acc0 += __shfl_xor(acc0, 32, 64);
        acc1 += __shfl_xor(acc1, 16, 64);
        acc1 += __shfl_xor(acc1, 32, 64);
        if (l4 == 0) {
            const int e0 = g0 * 16 + l15;
            if (e0 < E) out[e0] = acc0 + bias;
            if (g1 < ngrp) {
                const int e1 = g1 * 16 + l15;
                if (e1 < E) out[e1] = acc1 + bias;
            }
        }
    }
}

// ---------------------------------------------------------------------------
extern "C" void kernel_launch(void* const* d_in, const int* in_sizes, int n_in,
                              void* d_out, int out_size, void* d_ws, size_t ws_size,
                              hipStream_t stream)
{
    const float* x   = (const float*)d_in[0];
    const int*   ei  = (const int*)d_in[1];
    const float* W1  = (const float*)d_in[2];
    const float* b1  = (const float*)d_in[3];
    const float* g1  = (const float*)d_in[4];
    const float* be1 = (const float*)d_in[5];
    const float* W2  = (const float*)d_in[6];
    const float* b2  = (const float*)d_in[7];
    const float* g2  = (const float*)d_in[8];
    const float* be2 = (const float*)d_in[9];
    const float* W3  = (const float*)d_in[10];
    const float* b3  = (const float*)d_in[11];

    const int N = in_sizes[0] / CH;
    const int E = out_size;
    const int* src = ei;
    const int* dst = ei + E;

    const int S1_BLOCKS = 1024;
    const int S2_BLOCKS = 1024;
    const size_t ngblk = (size_t)((E + 63) >> 6) * 4;   // 16-edge groups, tile-padded

    // workspace layout (16B-aligned)
    unsigned short* u_bf = (unsigned short*)d_ws;              // N*128 bf16
    unsigned short* v_bf = u_bf + (size_t)N * CH;              // N*128 bf16
    uint2* h2raw = (uint2*)(v_bf + (size_t)N * CH);            // ngblk*8*64 uint2
    float* part1 = (float*)(h2raw + ngblk * 8 * 64);           // S1_BLOCKS*256
    float* part2 = part1 + (size_t)S1_BLOCKS * 256;            // S2_BLOCKS*256
    float* scale1 = part2 + (size_t)S2_BLOCKS * 256;
    float* shift1 = scale1 + CH;
    float* scale2 = shift1 + CH;
    float* shift2 = scale2 + CH;
    float* out = (float*)d_out;

    node_linear_kernel<<<(N + 63) / 64, 512, 0, stream>>>(x, W1, u_bf, v_bf, N);
    stats1_kernel<<<S1_BLOCKS, 512, 0, stream>>>(u_bf, v_bf, src, dst, part1, E);
    finalize_kernel<<<1, 1024, 0, stream>>>(part1, S1_BLOCKS, g1, be1, b1,
                                            scale1, shift1, 1.0f / (float)E);
    layer2_kernel<<<S2_BLOCKS, 512, 0, stream>>>(u_bf, v_bf, src, dst, b1, scale1, shift1,
                                                 W2, b2, h2raw, part2, E);
    finalize_kernel<<<1, 1024, 0, stream>>>(part2, S2_BLOCKS, g2, be2, nullptr,
                                            scale2, shift2, 1.0f / (float)E);
    output_kernel<<<2048, 256, 0, stream>>>(h2raw, scale2, shift2, W3, b3, out, E);
}